// Round 8
// baseline (145.834 us; speedup 1.0000x reference)
//
#include <hip/hip_runtime.h>

// EuclideanLoss: loss = (1/(B*N)) * sum_{b,n} w_n * sqrt(sum_d (x[b,n,d]-y[b,d,n])^2)
// w_n = 1.5 for n in {1,2}. B=32, N=8192, D=64, fp32. 128 MiB moved.
//
// R7: structure-invariance evidence (R0-R6 all ~43 us; L3-warm == HBM-cold)
// says the read path is pinned ~3 TB/s. Best per-byte config measured was R2
// (plain loads, 2048 blocks, 45 us INCLUDING a 2048-atomic drain that R5
// showed costs ~5.4 ns/atomic serialized). This round = R2 verbatim with the
// atomic replaced by a per-block ws store + tiny reduce kernel (R5's fix).
// Expect ~34 us main kernel; if >=40 us, the ~3 TB/s ceiling is environmental
// and we are at the roofline.

constexpr int B = 32;
constexpr int N = 8192;
constexpr int D = 64;
constexpr int HALF = D / 2;              // 32 d per wave
constexpr int NPB  = 128;                // n-values per block
constexpr int NBLK = (N / NPB) * B;      // 2048 partials

__global__ __launch_bounds__(256) void euclid_loss_kernel(
    const float* __restrict__ x,   // [B, N, D]
    const float* __restrict__ y,   // [B, D, N]
    float* __restrict__ ws)        // [NBLK] per-block partials
{
    const int tid    = threadIdx.x;
    const int wave   = tid >> 6;         // 0..3
    const int lane   = tid & 63;
    const int nchunk = wave >> 1;        // which 64-n group (0,1)
    const int half   = wave & 1;         // which d-half (0,1)
    const int n      = blockIdx.x * NPB + nchunk * 64 + lane;
    const int b      = blockIdx.y;

    const float* xp = x + ((size_t)b * N + n) * D + half * HALF;
    const float* yp = y + (size_t)b * D * N + (size_t)(half * HALF) * N + n;

    // 8 independent float4 (x) + 32 independent scalar (y, 256 B/wave-instr).
    float4 xv[8];
#pragma unroll
    for (int j = 0; j < 8; ++j)
        xv[j] = *reinterpret_cast<const float4*>(xp + 4 * j);

    float yv[HALF];
#pragma unroll
    for (int d = 0; d < HALF; ++d)
        yv[d] = yp[(size_t)d * N];

    float acc = 0.0f;
#pragma unroll
    for (int j = 0; j < 8; ++j) {
        const float d0 = xv[j].x - yv[4 * j + 0];
        const float d1 = xv[j].y - yv[4 * j + 1];
        const float d2 = xv[j].z - yv[4 * j + 2];
        const float d3 = xv[j].w - yv[4 * j + 3];
        acc += d0 * d0 + d1 * d1 + d2 * d2 + d3 * d3;
    }

    // Exchange d-half partial sums through LDS, combine before sqrt.
    __shared__ float part[2][NPB];
    part[half][nchunk * 64 + lane] = acc;    // 64 consecutive floats per wave
    __syncthreads();

    float v = 0.0f;
    if (tid < NPB) {
        const int n2 = blockIdx.x * NPB + tid;
        const float s = part[0][tid] + part[1][tid];
        const float w = (n2 == 1 || n2 == 2) ? 1.5f : 1.0f;
        v = w * __builtin_sqrtf(s);
    }

    // Waves 0,1 hold the 128 values (waves 2,3 contribute 0).
#pragma unroll
    for (int off = 32; off > 0; off >>= 1) v += __shfl_down(v, off, 64);

    __shared__ float wsum[4];
    if (lane == 0) wsum[wave] = v;
    __syncthreads();

    if (tid == 0)
        ws[blockIdx.y * gridDim.x + blockIdx.x] =
            wsum[0] + wsum[1] + wsum[2] + wsum[3];   // plain store, no atomic
}

__global__ __launch_bounds__(256) void reduce_kernel(
    const float* __restrict__ ws,  // [NBLK]
    float* __restrict__ out)       // [1]
{
    const int tid = threadIdx.x;
    float v = 0.0f;
#pragma unroll
    for (int j = 0; j < NBLK / (256 * 2); ++j) {   // 2 float2 per thread
        const float2 p = *reinterpret_cast<const float2*>(ws + j * 512 + tid * 2);
        v += p.x + p.y;
    }
#pragma unroll
    for (int off = 32; off > 0; off >>= 1) v += __shfl_down(v, off, 64);

    __shared__ float wsum[4];
    if ((tid & 63) == 0) wsum[tid >> 6] = v;
    __syncthreads();
    if (tid == 0)
        out[0] = (wsum[0] + wsum[1] + wsum[2] + wsum[3]) * (1.0f / (float)(B * N));
}

extern "C" void kernel_launch(void* const* d_in, const int* in_sizes, int n_in,
                              void* d_out, int out_size, void* d_ws, size_t ws_size,
                              hipStream_t stream) {
    const float* x = (const float*)d_in[0];
    const float* y = (const float*)d_in[1];
    float* out = (float*)d_out;
    float* ws  = (float*)d_ws;

    dim3 grid(N / NPB, B);               // (64, 32) = 2048 blocks
    euclid_loss_kernel<<<grid, 256, 0, stream>>>(x, y, ws);
    reduce_kernel<<<1, 256, 0, stream>>>(ws, out);
}